// Round 13
// baseline (198.791 us; speedup 1.0000x reference)
//
#include <hip/hip_runtime.h>
#include <hip/hip_bf16.h>
#include <math.h>

// ---------------- problem constants ----------------
#define NBATCH 4
#define HW     4096          // 64*64
#define NPIX   16384         // 4*64*64
#define SCALE  0.0625f       // 256^-0.5
#define QLOG2E (0.0625f * 1.44269504088896340736f)

typedef __attribute__((ext_vector_type(8))) short bf16x8;   // 8 bf16 (4 VGPRs)
typedef __attribute__((ext_vector_type(4))) float f32x4;    // MFMA C/D

__device__ __forceinline__ int pixmap(int b, int n, int p, int pos){
  // b==0: rows 2p,2p+1 (contiguous 128 px); b==1: cols 2p,2p+1, pos = h*2+wi
  return (b == 0) ? (n*HW + p*128 + pos)
                  : (n*HW + (pos >> 1)*64 + (p << 1) + (pos & 1));
}

__device__ __forceinline__ ushort f2b(float x){
  __hip_bfloat16 h = __float2bfloat16(x);
  return *reinterpret_cast<ushort*>(&h);
}
__device__ __forceinline__ float b2f(ushort u){
  __hip_bfloat16 h = *reinterpret_cast<__hip_bfloat16*>(&u);
  return __bfloat162float(h);
}
// truncation pack: 2 f32 -> 2 bf16 in one uint (2-3 VALU, compiler-known ops only)
__device__ __forceinline__ uint pk2t(float a, float b){
  return (__float_as_uint(a) >> 16) | (__float_as_uint(b) & 0xFFFF0000u);
}

// ---------------- K0a: Xb transpose of x + window-mean partials (fused) ----------------
__global__ __launch_bounds__(256) void k_xt(
    const float* __restrict__ x, ushort* __restrict__ Xb,
    float* __restrict__ pb0, float* __restrict__ pb1)
{
  __shared__ float T[32][257];
  const int n = blockIdx.y, blk = blockIdx.x, hw0 = blk * 32;
  const int tid = threadIdx.x;
  const int hl = tid & 31, cg = tid >> 5;
  #pragma unroll 8
  for(int i = 0; i < 32; i++){
    const int c = i*8 + cg;
    T[hl][c] = x[((size_t)(n*256 + c))*4096 + hw0 + hl];
  }
  __syncthreads();
  const int c0 = (tid & 31)*8, pbr = tid >> 5;
  #pragma unroll
  for(int i = 0; i < 4; i++){
    const int p = pbr + 8*i;
    union { bf16x8 v; ushort u[8]; } U;
    #pragma unroll
    for(int j = 0; j < 8; j++) U.u[j] = f2b(T[p][c0 + j]);
    *(bf16x8*)(Xb + ((size_t)(n*HW + hw0 + p))*256 + c0) = U.v;
  }
  // window-mean partials: thread = channel c (conflict-free LDS reads, fixed order)
  const int c = tid;
  float s0 = 0.f;
  float* p1 = pb1 + (((size_t)n*128 + blk)*16)*256 + c;
  #pragma unroll
  for(int j = 0; j < 16; j++){
    const float pj = T[2*j][c] + T[2*j+1][c];
    p1[(size_t)j*256] = pj;
    s0 += pj;
  }
  pb0[((size_t)n*128 + blk)*256 + c] = s0;
}

// ---------------- K0a2: reduce partials -> xwin (fp32, deterministic order) ----------------
__global__ __launch_bounds__(256) void k_xred(
    const float* __restrict__ pb0, const float* __restrict__ pb1,
    float* __restrict__ xwin)
{
  const int p = blockIdx.x;   // window 0..31
  const int n = blockIdx.y;
  const int c = threadIdx.x;
  float s = 0.f;
  #pragma unroll
  for(int i = 0; i < 4; i++)
    s += pb0[((size_t)n*128 + 4*p + i)*256 + c];
  xwin[((size_t)((0*NBATCH + n)*32 + p))*256 + c] = s * (1.f/128.f);
  const int half = p >> 4, j = p & 15;
  float s1 = 0.f;
  for(int h = 0; h < 64; h++)
    s1 += pb1[(((size_t)n*128 + 2*h + half)*16 + j)*256 + c];
  xwin[((size_t)((1*NBATCH + n)*32 + p))*256 + c] = s1 * (1.f/128.f);
}

// ---------------- K0b: fused weight transposes (Wt = Wqkv^T, WoT = Wo^T) ----------------
__global__ __launch_bounds__(256) void k_wprep(
    const float* __restrict__ Wqkv, const float* __restrict__ Wo,
    ushort* __restrict__ Wt, ushort* __restrict__ WoT)
{
  const int o = blockIdx.x, t = threadIdx.x;
  if(o < 768){
    Wt[(size_t)o*256 + t] = f2b(Wqkv[(size_t)t*768 + o]);
  } else {
    const int c = o - 768;
    WoT[(size_t)c*256 + t] = f2b(Wo[(size_t)t*256 + c]);
  }
}

// ---------------- K1: QKVb = Xb @ Wt^T + bqkv (q pre-scaled), V also -> Vt ----------------
__global__ __launch_bounds__(256) void k_qkv_mfma(
    const ushort* __restrict__ Xb, const ushort* __restrict__ Wt,
    const float* __restrict__ bqkv, ushort* __restrict__ QKVb,
    ushort* __restrict__ Vt)
{
  const int tid = threadIdx.x;
  const int l = tid & 63, w = tid >> 6;
  const int wr = w >> 1, wc = w & 1;
  const int q16 = l & 15, g = l >> 4;
  const int row0 = blockIdx.x*128 + wr*64;
  const int col0 = blockIdx.y*128 + wc*64;

  f32x4 acc[4][4];
  #pragma unroll
  for(int i = 0; i < 4; i++)
    #pragma unroll
    for(int j = 0; j < 4; j++) acc[i][j] = (f32x4){0,0,0,0};

  const ushort* Ab = Xb + (size_t)(row0 + q16)*256 + 8*g;
  const ushort* Bb = Wt + (size_t)(col0 + q16)*256 + 8*g;

  #pragma unroll
  for(int ks = 0; ks < 8; ks++){
    const int k0 = ks*32;
    bf16x8 a[4], b[4];
    #pragma unroll
    for(int i = 0; i < 4; i++) a[i] = *(const bf16x8*)(Ab + (size_t)(16*i)*256 + k0);
    #pragma unroll
    for(int j = 0; j < 4; j++) b[j] = *(const bf16x8*)(Bb + (size_t)(16*j)*256 + k0);
    #pragma unroll
    for(int i = 0; i < 4; i++)
      #pragma unroll
      for(int j = 0; j < 4; j++)
        acc[i][j] = __builtin_amdgcn_mfma_f32_16x16x32_bf16(a[i], b[j], acc[i][j], 0, 0, 0);
  }

  const int n = row0 >> 12, hwb = row0 & 4095;
  #pragma unroll
  for(int j = 0; j < 4; j++){
    const int col = col0 + 16*j + q16;
    const float bias = bqkv[col];
    const float sc = (col < 256) ? QLOG2E : 1.f;
    #pragma unroll
    for(int i = 0; i < 4; i++){
      ushort4 u;
      u.x = f2b((acc[i][j][0] + bias) * sc);
      u.y = f2b((acc[i][j][1] + bias) * sc);
      u.z = f2b((acc[i][j][2] + bias) * sc);
      u.w = f2b((acc[i][j][3] + bias) * sc);
      const int row = row0 + 16*i + 4*g;
      QKVb[(size_t)(row+0)*768 + col] = u.x;
      QKVb[(size_t)(row+1)*768 + col] = u.y;
      QKVb[(size_t)(row+2)*768 + col] = u.z;
      QKVb[(size_t)(row+3)*768 + col] = u.w;
      if(col >= 512){  // v-part: rows are consecutive pixels -> vectorized Vt store
        *(ushort4*)&Vt[((size_t)(n*256 + col - 512))*4096 + hwb + 16*i + 4*g] = u;
      }
    }
  }
}

// ---------------- K3: qwin/kwin = xwin @ Wqkv[:, :512] + bqkv (exact fp32) ----------------
__global__ __launch_bounds__(256) void k_win_gemm(
    const float* __restrict__ xwin, const float* __restrict__ Wqkv,
    const float* __restrict__ bqkv, float* __restrict__ qwin, float* __restrict__ kwin)
{
  __shared__ float xs[256];
  const int row = blockIdx.x;            // (b*4+n)*32+p
  const int tid = threadIdx.x;
  xs[tid] = xwin[(size_t)row*256 + tid];
  __syncthreads();
  #pragma unroll
  for(int half = 0; half < 2; half++){
    const int col = half*256 + tid;
    float s = 0.f;
    for(int k = 0; k < 256; k++) s += xs[k] * Wqkv[(size_t)k*768 + col];
    s += bqkv[col];
    if(half == 0) qwin[(size_t)row*256 + tid] = s;
    else          kwin[(size_t)row*256 + tid] = s;
  }
}

// ---------------- K4: 32x32 routing logits + stable top-2 ----------------
__global__ __launch_bounds__(256) void k_logits_top2(
    const float* __restrict__ qwin, const float* __restrict__ kwin, int* __restrict__ ridx)
{
  const int n = blockIdx.x, b = blockIdx.y;
  __shared__ float lg[32][32];
  const int base = ((b*NBATCH + n)*32)*256;
  for(int t = threadIdx.x; t < 1024; t += 256){
    const int p = t >> 5, q = t & 31;
    const float* qp = qwin + base + p*256;
    const float* kq = kwin + base + q*256;
    float s = 0.f;
    for(int c = 0; c < 256; c++) s += qp[c]*kq[c];
    lg[p][q] = s * SCALE;
  }
  __syncthreads();
  if(threadIdx.x < 32){
    const int p = threadIdx.x;
    float m0 = -INFINITY; int i0 = 0;
    for(int q = 0; q < 32; q++){ const float v = lg[p][q]; if(v > m0){ m0 = v; i0 = q; } }
    float m1 = -INFINITY; int i1 = 0;
    for(int q = 0; q < 32; q++){ if(q == i0) continue; const float v = lg[p][q]; if(v > m1){ m1 = v; i1 = q; } }
    const int o = ((b*NBATCH + n)*32 + p)*2;
    ridx[o] = i0; ridx[o+1] = i1;
  }
}

// ---------------- K5: MFMA routed attention, window-split wave pairs ----------------
// QK^T C-fragment reused directly as PV B-operand (permuted key order, see r5).
// NEW (r13): each (b,n,p,hd) handled by a PAIR of waves in one block — wave
// half=0 computes window r0's 4 chunks, half=1 computes r1's; partial
// (acc, rs) merge exactly through LDS (exp has no running max), full 8-m ILP
// per wave, 2x TLP (4096 waves -> 4/SIMD).
struct KVFrag { bf16x8 kf0, kf1, vf0, vf1; };

__device__ __forceinline__ KVFrag load_kv(
    const ushort* __restrict__ QKVb, const ushort* __restrict__ Vt,
    int b, int n, int wsel, int posb, int hd, int q16, int g)
{
  KVFrag f;
  const int kp0 = pixmap(b, n, wsel, posb + q16);
  f.kf0 = *(const bf16x8*)(QKVb + (size_t)kp0*768 + 256 + hd*32 + 8*g);
  const int kp1 = pixmap(b, n, wsel, posb + 16 + q16);
  f.kf1 = *(const bf16x8*)(QKVb + (size_t)kp1*768 + 256 + hd*32 + 8*g);
  if(b == 0){
    const ushort* base = Vt + ((size_t)(n*256 + hd*32 + q16))*4096 + wsel*128 + posb + 4*g;
    union { bf16x8 v; ushort4 h[2]; } U0, U1;
    U0.h[0] = *(const ushort4*)(base);
    U0.h[1] = *(const ushort4*)(base + 16);
    U1.h[0] = *(const ushort4*)(base + (size_t)16*4096);
    U1.h[1] = *(const ushort4*)(base + (size_t)16*4096 + 16);
    f.vf0 = U0.v; f.vf1 = U1.v;
  } else {
    const int h0 = (posb + 4*g) >> 1;
    const ushort* base = Vt + ((size_t)(n*256 + hd*32 + q16))*4096 + 2*wsel;
    union { bf16x8 v; uint u[4]; } U0, U1;
    U0.u[0] = *(const uint*)(base + (h0    )*64);
    U0.u[1] = *(const uint*)(base + (h0 + 1)*64);
    U0.u[2] = *(const uint*)(base + (h0 + 8)*64);
    U0.u[3] = *(const uint*)(base + (h0 + 9)*64);
    const ushort* base1 = base + (size_t)16*4096;
    U1.u[0] = *(const uint*)(base1 + (h0    )*64);
    U1.u[1] = *(const uint*)(base1 + (h0 + 1)*64);
    U1.u[2] = *(const uint*)(base1 + (h0 + 8)*64);
    U1.u[3] = *(const uint*)(base1 + (h0 + 9)*64);
    f.vf0 = U0.v; f.vf1 = U1.v;
  }
  return f;
}

__global__ __launch_bounds__(256) void k_attn_mfma(
    const ushort* __restrict__ QKVb, const ushort* __restrict__ Vt,
    const int* __restrict__ ridx, ushort* __restrict__ Ob)
{
  __shared__ float comb[2][64][76];   // [pair][lane][8m*8acc + 8rs], padded row=304B
  const int wv = threadIdx.x >> 6;
  const int pair = wv >> 1, half = wv & 1;
  int id = blockIdx.x*2 + pair;       // 2048 (b,n,p,hd) tuples
  const int hd = id & 7;  id >>= 3;
  const int p  = id & 31; id >>= 5;
  const int n  = id & 3;  id >>= 2;
  const int b  = id;
  const int l = threadIdx.x & 63;
  const int q16 = l & 15, g = l >> 4;

  const int ro = ((b*NBATCH + n)*32 + p)*2;
  const int wsel = ridx[ro + half];   // half 0 -> r0, half 1 -> r1

  // Q fragments (B-operand of S^T = K @ Q^T): rows of QKVb q-part (pre-scaled)
  int qpix[8];
  bf16x8 qf[8];
  #pragma unroll
  for(int m = 0; m < 8; m++){
    qpix[m] = pixmap(b, n, p, m*16 + q16);
    qf[m] = *(const bf16x8*)(QKVb + (size_t)qpix[m]*768 + hd*32 + 8*g);
  }

  f32x4 acc0[8], acc1[8];
  float rs[8];
  #pragma unroll
  for(int m = 0; m < 8; m++){
    acc0[m] = (f32x4){0,0,0,0}; acc1[m] = (f32x4){0,0,0,0}; rs[m] = 0.f;
  }

  #define COMPUTE(F)                                                            \
    __builtin_amdgcn_s_setprio(1);                                              \
    _Pragma("unroll")                                                           \
    for(int m = 0; m < 8; m++){                                                 \
      const f32x4 z = {0,0,0,0};                                                \
      f32x4 s0 = __builtin_amdgcn_mfma_f32_16x16x32_bf16((F).kf0, qf[m], z, 0, 0, 0); \
      f32x4 s1 = __builtin_amdgcn_mfma_f32_16x16x32_bf16((F).kf1, qf[m], z, 0, 0, 0); \
      const float e00 = exp2f(s0[0]), e01 = exp2f(s0[1]), e02 = exp2f(s0[2]), e03 = exp2f(s0[3]); \
      const float e10 = exp2f(s1[0]), e11 = exp2f(s1[1]), e12 = exp2f(s1[2]), e13 = exp2f(s1[3]); \
      rs[m] += ((e00+e01)+(e02+e03)) + ((e10+e11)+(e12+e13));                   \
      union { bf16x8 v; uint u[4]; } P;                                         \
      P.u[0] = pk2t(e00, e01);                                                  \
      P.u[1] = pk2t(e02, e03);                                                  \
      P.u[2] = pk2t(e10, e11);                                                  \
      P.u[3] = pk2t(e12, e13);                                                  \
      acc0[m] = __builtin_amdgcn_mfma_f32_16x16x32_bf16((F).vf0, P.v, acc0[m], 0, 0, 0); \
      acc1[m] = __builtin_amdgcn_mfma_f32_16x16x32_bf16((F).vf1, P.v, acc1[m], 0, 0, 0); \
    }                                                                           \
    __builtin_amdgcn_s_setprio(0);

  // this wave's window: 4 chunks, 1-ahead register double-buffer
  KVFrag fA = load_kv(QKVb, Vt, b, n, wsel, 0, hd, q16, g);
  {
    KVFrag fB = load_kv(QKVb, Vt, b, n, wsel, 32, hd, q16, g);
    COMPUTE(fA);
    fA = load_kv(QKVb, Vt, b, n, wsel, 64, hd, q16, g);
    COMPUTE(fB);
    fB = load_kv(QKVb, Vt, b, n, wsel, 96, hd, q16, g);
    COMPUTE(fA);
    COMPUTE(fB);
  }
  #undef COMPUTE

  // merge pair partials through LDS (exact: no max-shift, plain sums)
  float* cb = &comb[pair][l][0];
  if(half == 1){
    #pragma unroll
    for(int m = 0; m < 8; m++){
      *(float4*)(cb + m*8)     = (float4){acc0[m][0], acc0[m][1], acc0[m][2], acc0[m][3]};
      *(float4*)(cb + m*8 + 4) = (float4){acc1[m][0], acc1[m][1], acc1[m][2], acc1[m][3]};
      cb[64 + m] = rs[m];
    }
  }
  __syncthreads();
  if(half == 0){
    #pragma unroll
    for(int m = 0; m < 8; m++){
      const float4 a0 = *(const float4*)(cb + m*8);
      const float4 a1 = *(const float4*)(cb + m*8 + 4);
      acc0[m][0] += a0.x; acc0[m][1] += a0.y; acc0[m][2] += a0.z; acc0[m][3] += a0.w;
      acc1[m][0] += a1.x; acc1[m][1] += a1.y; acc1[m][2] += a1.z; acc1[m][3] += a1.w;
      rs[m] += cb[64 + m];
    }
    #pragma unroll
    for(int m = 0; m < 8; m++){
      float r = rs[m];
      r += __shfl_xor(r, 16);
      r += __shfl_xor(r, 32);
      rs[m] = 1.f / r;
    }
    #pragma unroll
    for(int m = 0; m < 8; m++){
      ushort* op = Ob + ((size_t)b*NPIX + qpix[m])*256 + hd*32 + 4*g;
      const float iv = rs[m];
      ushort4 o0 = { f2b(acc0[m][0]*iv), f2b(acc0[m][1]*iv), f2b(acc0[m][2]*iv), f2b(acc0[m][3]*iv) };
      ushort4 o1 = { f2b(acc1[m][0]*iv), f2b(acc1[m][1]*iv), f2b(acc1[m][2]*iv), f2b(acc1[m][3]*iv) };
      *(ushort4*)op = o0;
      *(ushort4*)(op + 16) = o1;
    }
  }
}

// ---------------- K6: Sb = bf16(O0 + O1 + 2*(dwconv3x3(v) + lepe_b)) ----------------
__global__ __launch_bounds__(256) void k_combine_lepe(
    const ushort* __restrict__ QKVb, const ushort* __restrict__ Ob0,
    const ushort* __restrict__ Ob1,
    const float* __restrict__ lw, const float* __restrict__ lb, ushort* __restrict__ Sb)
{
  const int pix = blockIdx.x;
  const int c = threadIdx.x;
  const int n = pix >> 12, rem = pix & 4095;
  const int h = rem >> 6, w = rem & 63;
  float conv = 0.f;
  #pragma unroll
  for(int kh = 0; kh < 3; kh++){
    const int hh = h + kh - 1;
    if(hh < 0 || hh >= 64) continue;
    #pragma unroll
    for(int kw = 0; kw < 3; kw++){
      const int wi = w + kw - 1;
      if(wi < 0 || wi >= 64) continue;
      const int np = (n*64 + hh)*64 + wi;
      conv += b2f(QKVb[(size_t)np*768 + 512 + c]) * lw[(kh*3 + kw)*256 + c];
    }
  }
  const size_t idx = (size_t)pix*256 + c;
  Sb[idx] = f2b(b2f(Ob0[idx]) + b2f(Ob1[idx]) + 2.f*(conv + lb[c]));
}

// ---------------- K7: OUT_nchw[c][pix] = WoT @ Sb^T + 2*bo (MFMA) ----------------
__global__ __launch_bounds__(256) void k_out_mfma(
    const ushort* __restrict__ Sb, const ushort* __restrict__ WoT,
    const float* __restrict__ bo, float* __restrict__ out)
{
  const int tid = threadIdx.x;
  const int l = tid & 63, w = tid >> 6;
  const int wr = w >> 1, wc = w & 1;
  const int q16 = l & 15, g = l >> 4;
  const int c0   = blockIdx.x*128 + wr*64;     // channel tile (M-dim)
  const int pix0 = blockIdx.y*128 + wc*64;     // pixel tile (N-dim)
  const int n = pix0 >> 12, rem0 = pix0 & 4095;

  f32x4 acc[4][4];
  #pragma unroll
  for(int i = 0; i < 4; i++)
    #pragma unroll
    for(int j = 0; j < 4; j++) acc[i][j] = (f32x4){0,0,0,0};

  const ushort* Ab = WoT + (size_t)(c0 + q16)*256 + 8*g;
  const ushort* Bb = Sb  + (size_t)(pix0 + q16)*256 + 8*g;

  #pragma unroll
  for(int ks = 0; ks < 8; ks++){
    const int k0 = ks*32;
    bf16x8 a[4], b[4];
    #pragma unroll
    for(int i = 0; i < 4; i++) a[i] = *(const bf16x8*)(Ab + (size_t)(16*i)*256 + k0);
    #pragma unroll
    for(int j = 0; j < 4; j++) b[j] = *(const bf16x8*)(Bb + (size_t)(16*j)*256 + k0);
    #pragma unroll
    for(int i = 0; i < 4; i++)
      #pragma unroll
      for(int j = 0; j < 4; j++)
        acc[i][j] = __builtin_amdgcn_mfma_f32_16x16x32_bf16(a[i], b[j], acc[i][j], 0, 0, 0);
  }

  float* outn = out + (size_t)n*256*4096;
  #pragma unroll
  for(int i = 0; i < 4; i++){
    #pragma unroll
    for(int r = 0; r < 4; r++){
      const int c = c0 + 16*i + 4*g + r;
      const float bias = 2.f*bo[c];
      #pragma unroll
      for(int j = 0; j < 4; j++){
        const int rem = rem0 + 16*j + q16;
        outn[(size_t)c*4096 + rem] = acc[i][j][r] + bias;
      }
    }
  }
}

// ---------------- launch ----------------
extern "C" void kernel_launch(void* const* d_in, const int* in_sizes, int n_in,
                              void* d_out, int out_size, void* d_ws, size_t ws_size,
                              hipStream_t stream)
{
  const float* x    = (const float*)d_in[0];
  const float* Wqkv = (const float*)d_in[1];
  const float* bqkv = (const float*)d_in[2];
  const float* Wo   = (const float*)d_in[3];
  const float* bo   = (const float*)d_in[4];
  const float* lw   = (const float*)d_in[5];
  const float* lb   = (const float*)d_in[6];
  float* out = (float*)d_out;

  // workspace layout (~77 MB)
  char* w = (char*)d_ws;
  ushort* Xb   = (ushort*)w; w += (size_t)NPIX*256*2;        // 8.4 MB
  ushort* Wt   = (ushort*)w; w += (size_t)768*256*2;         // 0.4 MB
  ushort* WoT  = (ushort*)w; w += (size_t)256*256*2;         // 0.13 MB
  ushort* QKVb = (ushort*)w; w += (size_t)NPIX*768*2;        // 25.2 MB
  ushort* Vt   = (ushort*)w; w += (size_t)NPIX*256*2;        // 8.4 MB
  ushort* Ob   = (ushort*)w; w += (size_t)2*NPIX*256*2;      // 16.8 MB (Ob0|Ob1)
  ushort* Sb   = (ushort*)w; w += (size_t)NPIX*256*2;        // 8.4 MB
  float*  pb0  = (float*)w;  w += (size_t)NBATCH*128*256*4;  // 0.5 MB
  float*  pb1  = (float*)w;  w += (size_t)NBATCH*128*16*256*4; // 8.4 MB
  float*  xwin = (float*)w;  w += (size_t)2*NBATCH*32*256*4; // 0.26 MB
  float*  qwin = (float*)w;  w += (size_t)2*NBATCH*32*256*4;
  float*  kwin = (float*)w;  w += (size_t)2*NBATCH*32*256*4;
  int*    ridx = (int*)w;    w += (size_t)2*NBATCH*32*2*4;

  ushort* Ob0 = Ob;
  ushort* Ob1 = Ob + (size_t)NPIX*256;

  k_xt          <<<dim3(128,NBATCH), 256, 0, stream>>>(x, Xb, pb0, pb1);
  k_xred        <<<dim3(32,NBATCH), 256, 0, stream>>>(pb0, pb1, xwin);
  k_wprep       <<<1024, 256, 0, stream>>>(Wqkv, Wo, Wt, WoT);
  k_qkv_mfma    <<<dim3(128,6), 256, 0, stream>>>(Xb, Wt, bqkv, QKVb, Vt);
  k_win_gemm    <<<256, 256, 0, stream>>>(xwin, Wqkv, bqkv, qwin, kwin);
  k_logits_top2 <<<dim3(NBATCH,2), 256, 0, stream>>>(qwin, kwin, ridx);
  k_attn_mfma   <<<1024, 256, 0, stream>>>(QKVb, Vt, ridx, Ob);
  k_combine_lepe<<<NPIX, 256, 0, stream>>>(QKVb, Ob0, Ob1, lw, lb, Sb);
  k_out_mfma    <<<dim3(2,128), 256, 0, stream>>>(Sb, WoT, bo, out);
}

// Round 14
// 175.365 us; speedup vs baseline: 1.1336x; 1.1336x over previous
//
#include <hip/hip_runtime.h>
#include <hip/hip_bf16.h>
#include <math.h>

// ---------------- problem constants ----------------
#define NBATCH 4
#define HW     4096          // 64*64
#define NPIX   16384         // 4*64*64
#define SCALE  0.0625f       // 256^-0.5
#define QLOG2E (0.0625f * 1.44269504088896340736f)

typedef __attribute__((ext_vector_type(8))) short bf16x8;   // 8 bf16 (4 VGPRs)
typedef __attribute__((ext_vector_type(4))) float f32x4;    // MFMA C/D

__device__ __forceinline__ int pixmap(int b, int n, int p, int pos){
  // b==0: rows 2p,2p+1 (contiguous 128 px); b==1: cols 2p,2p+1, pos = h*2+wi
  return (b == 0) ? (n*HW + p*128 + pos)
                  : (n*HW + (pos >> 1)*64 + (p << 1) + (pos & 1));
}

__device__ __forceinline__ ushort f2b(float x){
  __hip_bfloat16 h = __float2bfloat16(x);
  return *reinterpret_cast<ushort*>(&h);
}
__device__ __forceinline__ float b2f(ushort u){
  __hip_bfloat16 h = *reinterpret_cast<__hip_bfloat16*>(&u);
  return __bfloat162float(h);
}
// truncation pack: 2 f32 -> 2 bf16 in one uint (2-3 VALU, compiler-known ops only)
__device__ __forceinline__ uint pk2t(float a, float b){
  return (__float_as_uint(a) >> 16) | (__float_as_uint(b) & 0xFFFF0000u);
}

// ---------------- K0a: Xb transpose of x + window-mean partials (fused) ----------------
__global__ __launch_bounds__(256) void k_xt(
    const float* __restrict__ x, ushort* __restrict__ Xb,
    float* __restrict__ pb0, float* __restrict__ pb1)
{
  __shared__ float T[32][257];
  const int n = blockIdx.y, blk = blockIdx.x, hw0 = blk * 32;
  const int tid = threadIdx.x;
  const int hl = tid & 31, cg = tid >> 5;
  #pragma unroll 8
  for(int i = 0; i < 32; i++){
    const int c = i*8 + cg;
    T[hl][c] = x[((size_t)(n*256 + c))*4096 + hw0 + hl];
  }
  __syncthreads();
  const int c0 = (tid & 31)*8, pbr = tid >> 5;
  #pragma unroll
  for(int i = 0; i < 4; i++){
    const int p = pbr + 8*i;
    union { bf16x8 v; ushort u[8]; } U;
    #pragma unroll
    for(int j = 0; j < 8; j++) U.u[j] = f2b(T[p][c0 + j]);
    *(bf16x8*)(Xb + ((size_t)(n*HW + hw0 + p))*256 + c0) = U.v;
  }
  // window-mean partials: thread = channel c (conflict-free LDS reads, fixed order)
  const int c = tid;
  float s0 = 0.f;
  float* p1 = pb1 + (((size_t)n*128 + blk)*16)*256 + c;
  #pragma unroll
  for(int j = 0; j < 16; j++){
    const float pj = T[2*j][c] + T[2*j+1][c];
    p1[(size_t)j*256] = pj;
    s0 += pj;
  }
  pb0[((size_t)n*128 + blk)*256 + c] = s0;
}

// ---------------- K0b: fused weight transposes (Wt = Wqkv^T, WoT = Wo^T) ----------------
__global__ __launch_bounds__(256) void k_wprep(
    const float* __restrict__ Wqkv, const float* __restrict__ Wo,
    ushort* __restrict__ Wt, ushort* __restrict__ WoT)
{
  const int o = blockIdx.x, t = threadIdx.x;
  if(o < 768){
    Wt[(size_t)o*256 + t] = f2b(Wqkv[(size_t)t*768 + o]);
  } else {
    const int c = o - 768;
    WoT[(size_t)c*256 + t] = f2b(Wo[(size_t)t*256 + c]);
  }
}

// ---------------- K1: QKVb = Xb @ Wt^T + bqkv (q pre-scaled), V also -> Vt ----------------
__global__ __launch_bounds__(256) void k_qkv_mfma(
    const ushort* __restrict__ Xb, const ushort* __restrict__ Wt,
    const float* __restrict__ bqkv, ushort* __restrict__ QKVb,
    ushort* __restrict__ Vt)
{
  const int tid = threadIdx.x;
  const int l = tid & 63, w = tid >> 6;
  const int wr = w >> 1, wc = w & 1;
  const int q16 = l & 15, g = l >> 4;
  const int row0 = blockIdx.x*128 + wr*64;
  const int col0 = blockIdx.y*128 + wc*64;

  f32x4 acc[4][4];
  #pragma unroll
  for(int i = 0; i < 4; i++)
    #pragma unroll
    for(int j = 0; j < 4; j++) acc[i][j] = (f32x4){0,0,0,0};

  const ushort* Ab = Xb + (size_t)(row0 + q16)*256 + 8*g;
  const ushort* Bb = Wt + (size_t)(col0 + q16)*256 + 8*g;

  #pragma unroll
  for(int ks = 0; ks < 8; ks++){
    const int k0 = ks*32;
    bf16x8 a[4], b[4];
    #pragma unroll
    for(int i = 0; i < 4; i++) a[i] = *(const bf16x8*)(Ab + (size_t)(16*i)*256 + k0);
    #pragma unroll
    for(int j = 0; j < 4; j++) b[j] = *(const bf16x8*)(Bb + (size_t)(16*j)*256 + k0);
    #pragma unroll
    for(int i = 0; i < 4; i++)
      #pragma unroll
      for(int j = 0; j < 4; j++)
        acc[i][j] = __builtin_amdgcn_mfma_f32_16x16x32_bf16(a[i], b[j], acc[i][j], 0, 0, 0);
  }

  const int n = row0 >> 12, hwb = row0 & 4095;
  #pragma unroll
  for(int j = 0; j < 4; j++){
    const int col = col0 + 16*j + q16;
    const float bias = bqkv[col];
    const float sc = (col < 256) ? QLOG2E : 1.f;
    #pragma unroll
    for(int i = 0; i < 4; i++){
      ushort4 u;
      u.x = f2b((acc[i][j][0] + bias) * sc);
      u.y = f2b((acc[i][j][1] + bias) * sc);
      u.z = f2b((acc[i][j][2] + bias) * sc);
      u.w = f2b((acc[i][j][3] + bias) * sc);
      const int row = row0 + 16*i + 4*g;
      QKVb[(size_t)(row+0)*768 + col] = u.x;
      QKVb[(size_t)(row+1)*768 + col] = u.y;
      QKVb[(size_t)(row+2)*768 + col] = u.z;
      QKVb[(size_t)(row+3)*768 + col] = u.w;
      if(col >= 512){  // v-part: rows are consecutive pixels -> vectorized Vt store
        *(ushort4*)&Vt[((size_t)(n*256 + col - 512))*4096 + hwb + 16*i + 4*g] = u;
      }
    }
  }
}

// ---------------- K3: qwin/kwin GEMM with fused xwin reduction ----------------
// Each block reduces its own xwin row from pb0/pb1 (same summation order as the
// old k_xred -> bit-identical routing), then does the 256x512 fp32 GEMM row.
__global__ __launch_bounds__(256) void k_win_gemm(
    const float* __restrict__ pb0, const float* __restrict__ pb1,
    const float* __restrict__ Wqkv, const float* __restrict__ bqkv,
    float* __restrict__ qwin, float* __restrict__ kwin)
{
  __shared__ float xs[256];
  const int row = blockIdx.x;            // (b*4+n)*32+p
  const int tid = threadIdx.x;
  const int b = row >> 7, rem = row & 127, n = rem >> 5, p = rem & 31;
  float s = 0.f;
  if(b == 0){
    #pragma unroll
    for(int i = 0; i < 4; i++)
      s += pb0[((size_t)n*128 + 4*p + i)*256 + tid];
  } else {
    const int half = p >> 4, j = p & 15;
    for(int h = 0; h < 64; h++)
      s += pb1[(((size_t)n*128 + 2*h + half)*16 + j)*256 + tid];
  }
  xs[tid] = s * (1.f/128.f);
  __syncthreads();
  #pragma unroll
  for(int half = 0; half < 2; half++){
    const int col = half*256 + tid;
    float acc = 0.f;
    for(int k = 0; k < 256; k++) acc += xs[k] * Wqkv[(size_t)k*768 + col];
    acc += bqkv[col];
    if(half == 0) qwin[(size_t)row*256 + tid] = acc;
    else          kwin[(size_t)row*256 + tid] = acc;
  }
}

// ---------------- K4: 32x32 routing logits + stable top-2 ----------------
__global__ __launch_bounds__(256) void k_logits_top2(
    const float* __restrict__ qwin, const float* __restrict__ kwin, int* __restrict__ ridx)
{
  const int n = blockIdx.x, b = blockIdx.y;
  __shared__ float lg[32][32];
  const int base = ((b*NBATCH + n)*32)*256;
  for(int t = threadIdx.x; t < 1024; t += 256){
    const int p = t >> 5, q = t & 31;
    const float* qp = qwin + base + p*256;
    const float* kq = kwin + base + q*256;
    float s = 0.f;
    for(int c = 0; c < 256; c++) s += qp[c]*kq[c];
    lg[p][q] = s * SCALE;
  }
  __syncthreads();
  if(threadIdx.x < 32){
    const int p = threadIdx.x;
    float m0 = -INFINITY; int i0 = 0;
    for(int q = 0; q < 32; q++){ const float v = lg[p][q]; if(v > m0){ m0 = v; i0 = q; } }
    float m1 = -INFINITY; int i1 = 0;
    for(int q = 0; q < 32; q++){ if(q == i0) continue; const float v = lg[p][q]; if(v > m1){ m1 = v; i1 = q; } }
    const int o = ((b*NBATCH + n)*32 + p)*2;
    ridx[o] = i0; ridx[o+1] = i1;
  }
}

// ---------------- K5: MFMA routed attention (r10/r12 structure, trunc P-pack) ----------------
// QK^T C-fragment reused directly as PV B-operand (permuted key order, see r5);
// V^T A-fragments loaded in the same permuted order. 1-ahead reg double-buffer.
struct KVFrag { bf16x8 kf0, kf1, vf0, vf1; };

__device__ __forceinline__ KVFrag load_kv(
    const ushort* __restrict__ QKVb, const ushort* __restrict__ Vt,
    int b, int n, int wsel, int posb, int hd, int q16, int g)
{
  KVFrag f;
  const int kp0 = pixmap(b, n, wsel, posb + q16);
  f.kf0 = *(const bf16x8*)(QKVb + (size_t)kp0*768 + 256 + hd*32 + 8*g);
  const int kp1 = pixmap(b, n, wsel, posb + 16 + q16);
  f.kf1 = *(const bf16x8*)(QKVb + (size_t)kp1*768 + 256 + hd*32 + 8*g);
  if(b == 0){
    const ushort* base = Vt + ((size_t)(n*256 + hd*32 + q16))*4096 + wsel*128 + posb + 4*g;
    union { bf16x8 v; ushort4 h[2]; } U0, U1;
    U0.h[0] = *(const ushort4*)(base);
    U0.h[1] = *(const ushort4*)(base + 16);
    U1.h[0] = *(const ushort4*)(base + (size_t)16*4096);
    U1.h[1] = *(const ushort4*)(base + (size_t)16*4096 + 16);
    f.vf0 = U0.v; f.vf1 = U1.v;
  } else {
    const int h0 = (posb + 4*g) >> 1;
    const ushort* base = Vt + ((size_t)(n*256 + hd*32 + q16))*4096 + 2*wsel;
    union { bf16x8 v; uint u[4]; } U0, U1;
    U0.u[0] = *(const uint*)(base + (h0    )*64);
    U0.u[1] = *(const uint*)(base + (h0 + 1)*64);
    U0.u[2] = *(const uint*)(base + (h0 + 8)*64);
    U0.u[3] = *(const uint*)(base + (h0 + 9)*64);
    const ushort* base1 = base + (size_t)16*4096;
    U1.u[0] = *(const uint*)(base1 + (h0    )*64);
    U1.u[1] = *(const uint*)(base1 + (h0 + 1)*64);
    U1.u[2] = *(const uint*)(base1 + (h0 + 8)*64);
    U1.u[3] = *(const uint*)(base1 + (h0 + 9)*64);
    f.vf0 = U0.v; f.vf1 = U1.v;
  }
  return f;
}

__global__ __launch_bounds__(256) void k_attn_mfma(
    const ushort* __restrict__ QKVb, const ushort* __restrict__ Vt,
    const int* __restrict__ ridx, ushort* __restrict__ Ob)
{
  int id = blockIdx.x*4 + (threadIdx.x >> 6);   // 4 independent waves per block
  const int hd = id & 7;  id >>= 3;
  const int p  = id & 31; id >>= 5;
  const int n  = id & 3;  id >>= 2;
  const int b  = id;
  const int l = threadIdx.x & 63;
  const int q16 = l & 15, g = l >> 4;

  const int ro = ((b*NBATCH + n)*32 + p)*2;
  const int r0 = ridx[ro], r1 = ridx[ro+1];

  // Q fragments (B-operand of S^T = K @ Q^T): rows of QKVb q-part (pre-scaled)
  int qpix[8];
  bf16x8 qf[8];
  #pragma unroll
  for(int m = 0; m < 8; m++){
    qpix[m] = pixmap(b, n, p, m*16 + q16);
    qf[m] = *(const bf16x8*)(QKVb + (size_t)qpix[m]*768 + hd*32 + 8*g);
  }

  f32x4 acc0[8], acc1[8];
  float rs[8];
  #pragma unroll
  for(int m = 0; m < 8; m++){
    acc0[m] = (f32x4){0,0,0,0}; acc1[m] = (f32x4){0,0,0,0}; rs[m] = 0.f;
  }

  #define COMPUTE(F)                                                            \
    __builtin_amdgcn_s_setprio(1);                                              \
    _Pragma("unroll")                                                           \
    for(int m = 0; m < 8; m++){                                                 \
      const f32x4 z = {0,0,0,0};                                                \
      f32x4 s0 = __builtin_amdgcn_mfma_f32_16x16x32_bf16((F).kf0, qf[m], z, 0, 0, 0); \
      f32x4 s1 = __builtin_amdgcn_mfma_f32_16x16x32_bf16((F).kf1, qf[m], z, 0, 0, 0); \
      const float e00 = exp2f(s0[0]), e01 = exp2f(s0[1]), e02 = exp2f(s0[2]), e03 = exp2f(s0[3]); \
      const float e10 = exp2f(s1[0]), e11 = exp2f(s1[1]), e12 = exp2f(s1[2]), e13 = exp2f(s1[3]); \
      rs[m] += ((e00+e01)+(e02+e03)) + ((e10+e11)+(e12+e13));                   \
      union { bf16x8 v; uint u[4]; } P;                                         \
      P.u[0] = pk2t(e00, e01);                                                  \
      P.u[1] = pk2t(e02, e03);                                                  \
      P.u[2] = pk2t(e10, e11);                                                  \
      P.u[3] = pk2t(e12, e13);                                                  \
      acc0[m] = __builtin_amdgcn_mfma_f32_16x16x32_bf16((F).vf0, P.v, acc0[m], 0, 0, 0); \
      acc1[m] = __builtin_amdgcn_mfma_f32_16x16x32_bf16((F).vf1, P.v, acc1[m], 0, 0, 0); \
    }                                                                           \
    __builtin_amdgcn_s_setprio(0);

  // register double-buffer: load c+1 before computing c (named bufs, no copies)
  KVFrag fA = load_kv(QKVb, Vt, b, n, r0, 0, hd, q16, g);
  for(int cc = 0; cc < 8; cc += 2){
    const int w1 = (cc+1 < 4) ? r0 : r1;
    KVFrag fB = load_kv(QKVb, Vt, b, n, w1, (32*(cc+1)) & 127, hd, q16, g);
    COMPUTE(fA);
    if(cc + 2 < 8){
      const int w2 = (cc+2 < 4) ? r0 : r1;
      fA = load_kv(QKVb, Vt, b, n, w2, (32*(cc+2)) & 127, hd, q16, g);
    }
    COMPUTE(fB);
  }
  #undef COMPUTE

  #pragma unroll
  for(int m = 0; m < 8; m++){
    float r = rs[m];
    r += __shfl_xor(r, 16);
    r += __shfl_xor(r, 32);
    rs[m] = 1.f / r;
  }
  #pragma unroll
  for(int m = 0; m < 8; m++){
    ushort* op = Ob + ((size_t)b*NPIX + qpix[m])*256 + hd*32 + 4*g;
    const float iv = rs[m];
    ushort4 o0 = { f2b(acc0[m][0]*iv), f2b(acc0[m][1]*iv), f2b(acc0[m][2]*iv), f2b(acc0[m][3]*iv) };
    ushort4 o1 = { f2b(acc1[m][0]*iv), f2b(acc1[m][1]*iv), f2b(acc1[m][2]*iv), f2b(acc1[m][3]*iv) };
    *(ushort4*)op = o0;
    *(ushort4*)(op + 16) = o1;
  }
}

// ---------------- K6: Sb = bf16(O0 + O1 + 2*(dwconv3x3(v) + lepe_b)) ----------------
__global__ __launch_bounds__(256) void k_combine_lepe(
    const ushort* __restrict__ QKVb, const ushort* __restrict__ Ob0,
    const ushort* __restrict__ Ob1,
    const float* __restrict__ lw, const float* __restrict__ lb, ushort* __restrict__ Sb)
{
  const int pix = blockIdx.x;
  const int c = threadIdx.x;
  const int n = pix >> 12, rem = pix & 4095;
  const int h = rem >> 6, w = rem & 63;
  float conv = 0.f;
  #pragma unroll
  for(int kh = 0; kh < 3; kh++){
    const int hh = h + kh - 1;
    if(hh < 0 || hh >= 64) continue;
    #pragma unroll
    for(int kw = 0; kw < 3; kw++){
      const int wi = w + kw - 1;
      if(wi < 0 || wi >= 64) continue;
      const int np = (n*64 + hh)*64 + wi;
      conv += b2f(QKVb[(size_t)np*768 + 512 + c]) * lw[(kh*3 + kw)*256 + c];
    }
  }
  const size_t idx = (size_t)pix*256 + c;
  Sb[idx] = f2b(b2f(Ob0[idx]) + b2f(Ob1[idx]) + 2.f*(conv + lb[c]));
}

// ---------------- K7: OUT_nchw[c][pix] = WoT @ Sb^T + 2*bo (MFMA) ----------------
__global__ __launch_bounds__(256) void k_out_mfma(
    const ushort* __restrict__ Sb, const ushort* __restrict__ WoT,
    const float* __restrict__ bo, float* __restrict__ out)
{
  const int tid = threadIdx.x;
  const int l = tid & 63, w = tid >> 6;
  const int wr = w >> 1, wc = w & 1;
  const int q16 = l & 15, g = l >> 4;
  const int c0   = blockIdx.x*128 + wr*64;     // channel tile (M-dim)
  const int pix0 = blockIdx.y*128 + wc*64;     // pixel tile (N-dim)
  const int n = pix0 >> 12, rem0 = pix0 & 4095;

  f32x4 acc[4][4];
  #pragma unroll
  for(int i = 0; i < 4; i++)
    #pragma unroll
    for(int j = 0; j < 4; j++) acc[i][j] = (f32x4){0,0,0,0};

  const ushort* Ab = WoT + (size_t)(c0 + q16)*256 + 8*g;
  const ushort* Bb = Sb  + (size_t)(pix0 + q16)*256 + 8*g;

  #pragma unroll
  for(int ks = 0; ks < 8; ks++){
    const int k0 = ks*32;
    bf16x8 a[4], b[4];
    #pragma unroll
    for(int i = 0; i < 4; i++) a[i] = *(const bf16x8*)(Ab + (size_t)(16*i)*256 + k0);
    #pragma unroll
    for(int j = 0; j < 4; j++) b[j] = *(const bf16x8*)(Bb + (size_t)(16*j)*256 + k0);
    #pragma unroll
    for(int i = 0; i < 4; i++)
      #pragma unroll
      for(int j = 0; j < 4; j++)
        acc[i][j] = __builtin_amdgcn_mfma_f32_16x16x32_bf16(a[i], b[j], acc[i][j], 0, 0, 0);
  }

  float* outn = out + (size_t)n*256*4096;
  #pragma unroll
  for(int i = 0; i < 4; i++){
    #pragma unroll
    for(int r = 0; r < 4; r++){
      const int c = c0 + 16*i + 4*g + r;
      const float bias = 2.f*bo[c];
      #pragma unroll
      for(int j = 0; j < 4; j++){
        const int rem = rem0 + 16*j + q16;
        outn[(size_t)c*4096 + rem] = acc[i][j][r] + bias;
      }
    }
  }
}

// ---------------- launch ----------------
extern "C" void kernel_launch(void* const* d_in, const int* in_sizes, int n_in,
                              void* d_out, int out_size, void* d_ws, size_t ws_size,
                              hipStream_t stream)
{
  const float* x    = (const float*)d_in[0];
  const float* Wqkv = (const float*)d_in[1];
  const float* bqkv = (const float*)d_in[2];
  const float* Wo   = (const float*)d_in[3];
  const float* bo   = (const float*)d_in[4];
  const float* lw   = (const float*)d_in[5];
  const float* lb   = (const float*)d_in[6];
  float* out = (float*)d_out;

  // workspace layout (~77 MB)
  char* w = (char*)d_ws;
  ushort* Xb   = (ushort*)w; w += (size_t)NPIX*256*2;        // 8.4 MB
  ushort* Wt   = (ushort*)w; w += (size_t)768*256*2;         // 0.4 MB
  ushort* WoT  = (ushort*)w; w += (size_t)256*256*2;         // 0.13 MB
  ushort* QKVb = (ushort*)w; w += (size_t)NPIX*768*2;        // 25.2 MB
  ushort* Vt   = (ushort*)w; w += (size_t)NPIX*256*2;        // 8.4 MB
  ushort* Ob   = (ushort*)w; w += (size_t)2*NPIX*256*2;      // 16.8 MB (Ob0|Ob1)
  ushort* Sb   = (ushort*)w; w += (size_t)NPIX*256*2;        // 8.4 MB
  float*  pb0  = (float*)w;  w += (size_t)NBATCH*128*256*4;  // 0.5 MB
  float*  pb1  = (float*)w;  w += (size_t)NBATCH*128*16*256*4; // 8.4 MB
  float*  qwin = (float*)w;  w += (size_t)2*NBATCH*32*256*4;
  float*  kwin = (float*)w;  w += (size_t)2*NBATCH*32*256*4;
  int*    ridx = (int*)w;    w += (size_t)2*NBATCH*32*2*4;

  ushort* Ob0 = Ob;
  ushort* Ob1 = Ob + (size_t)NPIX*256;

  k_xt          <<<dim3(128,NBATCH), 256, 0, stream>>>(x, Xb, pb0, pb1);
  k_wprep       <<<1024, 256, 0, stream>>>(Wqkv, Wo, Wt, WoT);
  k_qkv_mfma    <<<dim3(128,6), 256, 0, stream>>>(Xb, Wt, bqkv, QKVb, Vt);
  k_win_gemm    <<<256, 256, 0, stream>>>(pb0, pb1, Wqkv, bqkv, qwin, kwin);
  k_logits_top2 <<<dim3(NBATCH,2), 256, 0, stream>>>(qwin, kwin, ridx);
  k_attn_mfma   <<<512, 256, 0, stream>>>(QKVb, Vt, ridx, Ob);
  k_combine_lepe<<<NPIX, 256, 0, stream>>>(QKVb, Ob0, Ob1, lw, lb, Sb);
  k_out_mfma    <<<dim3(2,128), 256, 0, stream>>>(Sb, WoT, bo, out);
}